// Round 21
// baseline (847.386 us; speedup 1.0000x reference)
//
#include <hip/hip_runtime.h>
#include <math.h>

#define NSEQ 8192
#define BATCH 4
#define DIM 256
#define HEADS 8
#define DHEAD 32
#define NB 110
#define INNER 256
#define FFDIM 1024
#define MROWS (BATCH * NSEQ)   // 32768 rows
#define BH (BATCH * HEADS)     // 32

typedef __attribute__((ext_vector_type(8))) short bf16x8;
typedef __attribute__((ext_vector_type(4))) short bf16x4;
typedef __attribute__((ext_vector_type(4))) float f32x4;

typedef __attribute__((address_space(1))) const void* gas_cvp;
typedef __attribute__((address_space(3))) void* las_vp;

constexpr float c_dn = 0.42044820762685725f;     // 32^-0.25
constexpr float c_diagf = 0.08838834764831845f;  // 0.5*dn*dn
constexpr float c_ratio = 0.09534625892455922f;  // 110^-0.5

__device__ __forceinline__ unsigned short f2b(float f) {
    unsigned u = __float_as_uint(f);
    unsigned r = (u + 0x7FFFu + ((u >> 16) & 1u)) >> 16;
    return (unsigned short)r;
}
__device__ __forceinline__ float b2f(unsigned short u) {
    return __uint_as_float((unsigned)u << 16);
}

// ---------------- util ----------------
__global__ __launch_bounds__(256) void bcat_kernel(const float* __restrict__ bq,
                                                   const float* __restrict__ bk,
                                                   const float* __restrict__ bv,
                                                   float* __restrict__ out) {
    int l = blockIdx.x, t = threadIdx.x;
    out[l * 768 + t] = bq[l * 256 + t];
    out[l * 768 + 256 + t] = bk[l * 256 + t];
    out[l * 768 + 512 + t] = bv[l * 256 + t];
}

// ---------------- layer-0 entry: y = LN(x) AND hb = bf16(x) (folded cvt) ----------------
__global__ __launch_bounds__(256) void ln_kernel(const float* __restrict__ x,
                                                 const float* __restrict__ g,
                                                 const float* __restrict__ bta,
                                                 unsigned short* __restrict__ y,
                                                 unsigned short* __restrict__ hb) {
    int wave = threadIdx.x >> 6, lane = threadIdx.x & 63;
    int row = blockIdx.x * 4 + wave;
    const float* xr = x + (size_t)row * DIM;
    float4 v = *(const float4*)(xr + lane * 4);
    bf16x4 hcast;
    hcast[0] = (short)f2b(v.x);
    hcast[1] = (short)f2b(v.y);
    hcast[2] = (short)f2b(v.z);
    hcast[3] = (short)f2b(v.w);
    *(bf16x4*)(hb + (size_t)row * DIM + lane * 4) = hcast;
    float s = v.x + v.y + v.z + v.w;
    float sq = v.x * v.x + v.y * v.y + v.z * v.z + v.w * v.w;
    #pragma unroll
    for (int off = 32; off; off >>= 1) {
        s += __shfl_xor(s, off);
        sq += __shfl_xor(sq, off);
    }
    float mean = s * (1.0f / DIM);
    float var = sq * (1.0f / DIM) - mean * mean;
    float rstd = rsqrtf(var + 1e-5f);
    float4 gg = *(const float4*)(g + lane * 4);
    float4 bb = *(const float4*)(bta + lane * 4);
    bf16x4 o;
    o[0] = (short)f2b((v.x - mean) * rstd * gg.x + bb.x);
    o[1] = (short)f2b((v.y - mean) * rstd * gg.y + bb.y);
    o[2] = (short)f2b((v.z - mean) * rstd * gg.z + bb.z);
    o[3] = (short)f2b((v.w - mean) * rstd * gg.w + bb.w);
    *(bf16x4*)(y + (size_t)row * DIM + lane * 4) = o;
}

// ---------------- weight transpose+convert: out[l][n][k] = bf16(in[l][k][n]) ----------------
__global__ __launch_bounds__(256) void wt_kernel(const float* __restrict__ in,
                                                 unsigned short* __restrict__ out,
                                                 int K, int Nn, int lstride) {
    __shared__ float t32[32][33];
    int l = blockIdx.z;
    const float* inp = in + (size_t)l * K * Nn;
    unsigned short* outp = out + (size_t)l * lstride;
    int k0 = blockIdx.x * 32, n0 = blockIdx.y * 32;
    int tx = threadIdx.x & 31, ty = threadIdx.x >> 5;
    #pragma unroll
    for (int i = 0; i < 4; ++i)
        t32[ty + i * 8][tx] = inp[(size_t)(k0 + ty + i * 8) * Nn + n0 + tx];
    __syncthreads();
    #pragma unroll
    for (int i = 0; i < 4; ++i) {
        int r = ty + i * 8;  // n within tile
        outp[(size_t)(n0 + r) * K + k0 + tx] = f2b(t32[tx][r]);
    }
}

// ---------------- bf16 MFMA GEMM, 2-buffer pipeline + XCD swizzle (QKV) ----------------
// EPI 0: +bias -> bf16 (LDS epilogue)   EPI 2: gelu(+bias) -> bf16 (scalar epilogue)
// EPI 3: +bias -> bf16 segmented (LDS epilogue)
template <int EPI>
__global__ __launch_bounds__(256) void gemm_mfma(const unsigned short* __restrict__ A,
                                                 const unsigned short* __restrict__ Wt,
                                                 const float* __restrict__ bias,
                                                 void* __restrict__ Cv,
                                                 int Nn, int K) {
    __shared__ __align__(16) unsigned short pool[16384];   // As[2][4096] | Bs[2][4096]; C-tile reuse
    unsigned short* AsP = pool;
    unsigned short* BsP = pool + 8192;
    int tid = threadIdx.x;
    int nwg = gridDim.x * gridDim.y;
    int orig = blockIdx.y * gridDim.x + blockIdx.x;
    int swz = (orig & 7) * (nwg >> 3) + (orig >> 3);
    int m0 = (swz / gridDim.x) * 128, n0 = (swz % gridDim.x) * 128;
    int wave = tid >> 6, lane = tid & 63;
    int wm = (wave >> 1) * 64, wn = (wave & 1) * 64;
    int lr = lane & 15, lg = lane >> 4;
    f32x4 acc[4][4];
    #pragma unroll
    for (int i = 0; i < 4; ++i)
        #pragma unroll
        for (int j = 0; j < 4; ++j) acc[i][j] = (f32x4){0.f, 0.f, 0.f, 0.f};

    int rowS[2], chS[2];
    #pragma unroll
    for (int j = 0; j < 2; ++j) {
        int f = wave * 128 + j * 64 + lane;
        rowS[j] = f >> 2;
        chS[j] = ((f & 3) ^ ((rowS[j] >> 1) & 3)) * 8;
    }
    int rdA[4], rdB[4];
    #pragma unroll
    for (int i = 0; i < 4; ++i) {
        int ra = wm + i * 16 + lr;
        rdA[i] = ra * 32 + (lg ^ ((ra >> 1) & 3)) * 8;
        int rb = wn + i * 16 + lr;
        rdB[i] = rb * 32 + (lg ^ ((rb >> 1) & 3)) * 8;
    }

    const int NT = K >> 5;
    #pragma unroll
    for (int j = 0; j < 2; ++j) {
        const unsigned short* srcA = A + (size_t)(m0 + rowS[j]) * K + chS[j];
        __builtin_amdgcn_global_load_lds((gas_cvp)srcA,
                                         (las_vp)(AsP + wave * 1024 + j * 512), 16, 0, 0);
        const unsigned short* srcB = Wt + (size_t)(n0 + rowS[j]) * K + chS[j];
        __builtin_amdgcn_global_load_lds((gas_cvp)srcB,
                                         (las_vp)(BsP + wave * 1024 + j * 512), 16, 0, 0);
    }
    for (int kt = 0; kt < NT; ++kt) {
        int cur = kt & 1;
        if (kt + 1 < NT) {
            int nxt = cur ^ 1;
            int koff = (kt + 1) * 32;
            #pragma unroll
            for (int j = 0; j < 2; ++j) {
                const unsigned short* srcA = A + (size_t)(m0 + rowS[j]) * K + koff + chS[j];
                __builtin_amdgcn_global_load_lds((gas_cvp)srcA,
                                                 (las_vp)(AsP + nxt * 4096 + wave * 1024 + j * 512), 16, 0, 0);
                const unsigned short* srcB = Wt + (size_t)(n0 + rowS[j]) * K + koff + chS[j];
                __builtin_amdgcn_global_load_lds((gas_cvp)srcB,
                                                 (las_vp)(BsP + nxt * 4096 + wave * 1024 + j * 512), 16, 0, 0);
            }
            asm volatile("s_waitcnt vmcnt(4)" ::: "memory");
        } else {
            asm volatile("s_waitcnt vmcnt(0)" ::: "memory");
        }
        __builtin_amdgcn_s_barrier();
        __builtin_amdgcn_sched_barrier(0);
        bf16x8 af[4], bfv[4];
        #pragma unroll
        for (int i = 0; i < 4; ++i) af[i] = *(bf16x8*)&AsP[cur * 4096 + rdA[i]];
        #pragma unroll
        for (int j = 0; j < 4; ++j) bfv[j] = *(bf16x8*)&BsP[cur * 4096 + rdB[j]];
        #pragma unroll
        for (int i = 0; i < 4; ++i)
            #pragma unroll
            for (int j = 0; j < 4; ++j)
                acc[i][j] = __builtin_amdgcn_mfma_f32_16x16x32_bf16(af[i], bfv[j], acc[i][j], 0, 0, 0);
        __builtin_amdgcn_sched_barrier(0);
        __builtin_amdgcn_s_barrier();
    }

    if (EPI == 2) {
        #pragma unroll
        for (int i = 0; i < 4; ++i) {
            #pragma unroll
            for (int j = 0; j < 4; ++j) {
                int col = n0 + wn + j * 16 + lr;
                float bv = bias[col];
                #pragma unroll
                for (int r = 0; r < 4; ++r) {
                    int row = m0 + wm + i * 16 + lg * 4 + r;
                    float u = acc[i][j][r] + bv;
                    float t = 1.5957691216057308f * (u + 0.044715f * u * u * u);
                    float gv = u / (1.0f + __expf(-t));
                    ((unsigned short*)Cv)[(size_t)row * Nn + col] = f2b(gv);
                }
            }
        }
    } else {
        // LDS-transposed bf16 epilogue
        #pragma unroll
        for (int i = 0; i < 4; ++i) {
            #pragma unroll
            for (int j = 0; j < 4; ++j) {
                int tcol = wn + j * 16 + lr;
                float bv = bias[n0 + tcol];
                #pragma unroll
                for (int r = 0; r < 4; ++r) {
                    int trow = wm + i * 16 + lg * 4 + r;
                    float c = acc[i][j][r] + bv;
                    pool[trow * 128 + (((tcol >> 3) ^ (trow & 7)) << 3) + (tcol & 7)] = f2b(c);
                }
            }
        }
        __syncthreads();
        #pragma unroll
        for (int cch = 0; cch < 8; ++cch) {
            int g = cch * 256 + tid;
            int row = g >> 4, cc = g & 15;
            bf16x8 val = *(bf16x8*)&pool[row * 128 + ((cc ^ (row & 7)) << 3)];
            int grow = m0 + row;
            int gcol = n0 + cc * 8;
            if (EPI == 3) {
                size_t idx = (size_t)(gcol >> 8) * ((size_t)MROWS * DIM) + (size_t)grow * 256 + (gcol & 255);
                *(bf16x8*)((unsigned short*)Cv + idx) = val;
            } else {
                *(bf16x8*)((unsigned short*)Cv + (size_t)grow * Nn + gcol) = val;
            }
        }
    }
}

// ---------------- gemm_wide: 128x256 tile for FFN1 (gelu epilogue) ----------------
// Wave owns 64 rows x 128 cols: 32 MFMA + 12 ds_read per barrier pair (vs 16+8 in 128x128).
// Grid (4, MROWS/128) = 1024 blocks, XCD-swizzled; LDS 48KB; 2-buffer counted-vmcnt staging.
__global__ __launch_bounds__(256) void gemm_wide(const unsigned short* __restrict__ A,
                                                 const unsigned short* __restrict__ Wt,
                                                 const float* __restrict__ bias,
                                                 unsigned short* __restrict__ Cv,
                                                 int Nn, int K) {
    __shared__ __align__(16) unsigned short AsP[2 * 4096];   // 128x32 per buf
    __shared__ __align__(16) unsigned short BsP[2 * 8192];   // 256x32 per buf
    int tid = threadIdx.x;
    int nwg = gridDim.x * gridDim.y;
    int orig = blockIdx.y * gridDim.x + blockIdx.x;
    int swz = (orig & 7) * (nwg >> 3) + (orig >> 3);
    int m0 = (swz / gridDim.x) * 128, n0 = (swz % gridDim.x) * 256;
    int wave = tid >> 6, lane = tid & 63;
    int wm = (wave >> 1) * 64, wn = (wave & 1) * 128;
    int lr = lane & 15, lg = lane >> 4;
    f32x4 acc[4][8];
    #pragma unroll
    for (int i = 0; i < 4; ++i)
        #pragma unroll
        for (int j = 0; j < 8; ++j) acc[i][j] = (f32x4){0.f, 0.f, 0.f, 0.f};

    int rowSA[2], chSA[2];
    #pragma unroll
    for (int j = 0; j < 2; ++j) {
        int f = wave * 128 + j * 64 + lane;
        rowSA[j] = f >> 2;
        chSA[j] = ((f & 3) ^ ((rowSA[j] >> 1) & 3)) * 8;
    }
    int rowSB[4], chSB[4];
    #pragma unroll
    for (int j = 0; j < 4; ++j) {
        int f = wave * 256 + j * 64 + lane;
        rowSB[j] = f >> 2;   // 0..255
        chSB[j] = ((f & 3) ^ ((rowSB[j] >> 1) & 3)) * 8;
    }
    int rdA[4], rdB[8];
    #pragma unroll
    for (int i = 0; i < 4; ++i) {
        int ra = wm + i * 16 + lr;
        rdA[i] = ra * 32 + (lg ^ ((ra >> 1) & 3)) * 8;
    }
    #pragma unroll
    for (int j = 0; j < 8; ++j) {
        int rb = wn + j * 16 + lr;
        rdB[j] = rb * 32 + (lg ^ ((rb >> 1) & 3)) * 8;
    }

    const int NT = K >> 5;
    // prologue: stage tile 0
    #pragma unroll
    for (int j = 0; j < 2; ++j) {
        const unsigned short* srcA = A + (size_t)(m0 + rowSA[j]) * K + chSA[j];
        __builtin_amdgcn_global_load_lds((gas_cvp)srcA,
                                         (las_vp)(AsP + wave * 1024 + j * 512), 16, 0, 0);
    }
    #pragma unroll
    for (int j = 0; j < 4; ++j) {
        const unsigned short* srcB = Wt + (size_t)(n0 + rowSB[j]) * K + chSB[j];
        __builtin_amdgcn_global_load_lds((gas_cvp)srcB,
                                         (las_vp)(BsP + wave * 2048 + j * 512), 16, 0, 0);
    }
    for (int kt = 0; kt < NT; ++kt) {
        int cur = kt & 1;
        if (kt + 1 < NT) {
            int nxt = cur ^ 1;
            int koff = (kt + 1) * 32;
            #pragma unroll
            for (int j = 0; j < 2; ++j) {
                const unsigned short* srcA = A + (size_t)(m0 + rowSA[j]) * K + koff + chSA[j];
                __builtin_amdgcn_global_load_lds((gas_cvp)srcA,
                                                 (las_vp)(AsP + nxt * 4096 + wave * 1024 + j * 512), 16, 0, 0);
            }
            #pragma unroll
            for (int j = 0; j < 4; ++j) {
                const unsigned short* srcB = Wt + (size_t)(n0 + rowSB[j]) * K + koff + chSB[j];
                __builtin_amdgcn_global_load_lds((gas_cvp)srcB,
                                                 (las_vp)(BsP + nxt * 8192 + wave * 2048 + j * 512), 16, 0, 0);
            }
            asm volatile("s_waitcnt vmcnt(6)" ::: "memory");
        } else {
            asm volatile("s_waitcnt vmcnt(0)" ::: "memory");
        }
        __builtin_amdgcn_s_barrier();
        __builtin_amdgcn_sched_barrier(0);
        bf16x8 af[4], bfv[8];
        #pragma unroll
        for (int i = 0; i < 4; ++i) af[i] = *(bf16x8*)&AsP[cur * 4096 + rdA[i]];
        #pragma unroll
        for (int j = 0; j < 8; ++j) bfv[j] = *(bf16x8*)&BsP[cur * 8192 + rdB[j]];
        #pragma unroll
        for (int i = 0; i < 4; ++i)
            #pragma unroll
            for (int j = 0; j < 8; ++j)
                acc[i][j] = __builtin_amdgcn_mfma_f32_16x16x32_bf16(af[i], bfv[j], acc[i][j], 0, 0, 0);
        __builtin_amdgcn_sched_barrier(0);
        __builtin_amdgcn_s_barrier();
    }

    // scalar gelu epilogue
    #pragma unroll
    for (int i = 0; i < 4; ++i) {
        #pragma unroll
        for (int j = 0; j < 8; ++j) {
            int col = n0 + wn + j * 16 + lr;
            float bv = bias[col];
            #pragma unroll
            for (int r = 0; r < 4; ++r) {
                int row = m0 + wm + i * 16 + lg * 4 + r;
                float u = acc[i][j][r] + bv;
                float t = 1.5957691216057308f * (u + 0.044715f * u * u * u);
                float gv = u / (1.0f + __expf(-t));
                Cv[(size_t)row * Nn + col] = f2b(gv);
            }
        }
    }
}

// ---------------- gemm_ln: C=A@Wt^T+bias+res(bf16) -> h(bf16 or f32); optional fused LN -> y ----------------
template <int DO_LN, int F32OUT>
__global__ __launch_bounds__(256) void gemm_ln(const unsigned short* __restrict__ A,
                                               const unsigned short* __restrict__ Wt,
                                               const float* __restrict__ bias,
                                               const unsigned short* __restrict__ res,
                                               void* __restrict__ hout,
                                               unsigned short* __restrict__ yout,
                                               const float* __restrict__ gam,
                                               const float* __restrict__ bet,
                                               int K) {
    __shared__ __align__(16) unsigned short As[2][64 * 32];
    __shared__ __align__(16) unsigned short Bs[2][256 * 32];
    int tid = threadIdx.x;
    int nwg = gridDim.y;
    int orig = blockIdx.y;
    int swz = (orig & 7) * (nwg >> 3) + (orig >> 3);
    int m0 = swz * 64;
    int wave = tid >> 6, lane = tid & 63;
    int lr = lane & 15, lg = lane >> 4;

    f32x4 acc[16];
    #pragma unroll
    for (int j = 0; j < 16; ++j) acc[j] = (f32x4){0.f, 0.f, 0.f, 0.f};

    int fA = wave * 64 + lane;
    int rowA = fA >> 2, chA = ((fA & 3) ^ ((rowA >> 1) & 3)) * 8;
    int rowB[4], chB[4];
    #pragma unroll
    for (int j = 0; j < 4; ++j) {
        int f = wave * 256 + j * 64 + lane;
        rowB[j] = f >> 2;
        chB[j] = ((f & 3) ^ ((rowB[j] >> 1) & 3)) * 8;
    }
    int raA = wave * 16 + lr;
    int rdAo = raA * 32 + (lg ^ ((raA >> 1) & 3)) * 8;
    int rdBo[16];
    #pragma unroll
    for (int j = 0; j < 16; ++j) {
        int rb = j * 16 + lr;
        rdBo[j] = rb * 32 + (lg ^ ((rb >> 1) & 3)) * 8;
    }

    const int NT = K >> 5;
    {
        const unsigned short* srcA = A + (size_t)(m0 + rowA) * K + chA;
        __builtin_amdgcn_global_load_lds((gas_cvp)srcA, (las_vp)(&As[0][wave * 512]), 16, 0, 0);
        #pragma unroll
        for (int j = 0; j < 4; ++j) {
            const unsigned short* srcB = Wt + (size_t)rowB[j] * K + chB[j];
            __builtin_amdgcn_global_load_lds((gas_cvp)srcB, (las_vp)(&Bs[0][wave * 2048 + j * 512]), 16, 0, 0);
        }
    }
    for (int kt = 0; kt < NT; ++kt) {
        int cur = kt & 1;
        if (kt + 1 < NT) {
            int nxt = cur ^ 1;
            int koff = (kt + 1) * 32;
            const unsigned short* srcA = A + (size_t)(m0 + rowA) * K + koff + chA;
            __builtin_amdgcn_global_load_lds((gas_cvp)srcA, (las_vp)(&As[nxt][wave * 512]), 16, 0, 0);
            #pragma unroll
            for (int j = 0; j < 4; ++j) {
                const unsigned short* srcB = Wt + (size_t)rowB[j] * K + koff + chB[j];
                __builtin_amdgcn_global_load_lds((gas_cvp)srcB, (las_vp)(&Bs[nxt][wave * 2048 + j * 512]), 16, 0, 0);
            }
            asm volatile("s_waitcnt vmcnt(5)" ::: "memory");
        } else {
            asm volatile("s_waitcnt vmcnt(0)" ::: "memory");
        }
        __builtin_amdgcn_s_barrier();
        __builtin_amdgcn_sched_barrier(0);
        bf16x8 af = *(bf16x8*)&As[cur][rdAo];
        #pragma unroll
        for (int j = 0; j < 16; ++j) {
            bf16x8 bv = *(bf16x8*)&Bs[cur][rdBo[j]];
            acc[j] = __builtin_amdgcn_mfma_f32_16x16x32_bf16(af, bv, acc[j], 0, 0, 0);
        }
        __builtin_amdgcn_sched_barrier(0);
        __builtin_amdgcn_s_barrier();
    }

    float rs[4] = {0.f, 0.f, 0.f, 0.f};
    float rq[4] = {0.f, 0.f, 0.f, 0.f};
    #pragma unroll
    for (int j = 0; j < 16; ++j) {
        int col = j * 16 + lr;
        float bv = bias[col];
        #pragma unroll
        for (int r = 0; r < 4; ++r) {
            int row = m0 + wave * 16 + lg * 4 + r;
            float c = acc[j][r] + bv + b2f(res[(size_t)row * 256 + col]);
            if (F32OUT) ((float*)hout)[(size_t)row * 256 + col] = c;
            else ((unsigned short*)hout)[(size_t)row * 256 + col] = f2b(c);
            acc[j][r] = c;
            if (DO_LN) { rs[r] += c; rq[r] += c * c; }
        }
    }
    if (DO_LN) {
        #pragma unroll
        for (int r = 0; r < 4; ++r) {
            float s = rs[r], sq = rq[r];
            s += __shfl_xor(s, 1);  sq += __shfl_xor(sq, 1);
            s += __shfl_xor(s, 2);  sq += __shfl_xor(sq, 2);
            s += __shfl_xor(s, 4);  sq += __shfl_xor(sq, 4);
            s += __shfl_xor(s, 8);  sq += __shfl_xor(sq, 8);
            rs[r] = s; rq[r] = sq;
        }
        #pragma unroll
        for (int r = 0; r < 4; ++r) {
            float mean = rs[r] * (1.0f / 256.0f);
            float var = rq[r] * (1.0f / 256.0f) - mean * mean;
            rs[r] = mean;
            rq[r] = rsqrtf(var + 1e-5f);
        }
        #pragma unroll
        for (int j = 0; j < 16; ++j) {
            int col = j * 16 + lr;
            float gv = gam[col], bb = bet[col];
            #pragma unroll
            for (int r = 0; r < 4; ++r) {
                int row = m0 + wave * 16 + lg * 4 + r;
                float yv = (acc[j][r] - rs[r]) * rq[r] * gv + bb;
                yout[(size_t)row * 256 + col] = f2b(yv);
            }
        }
    }
}

// ---------------- kmaxg (+ folded ctx zeroing) ----------------
__global__ __launch_bounds__(256) void kmaxg_kernel(const unsigned short* __restrict__ k,
                                                    const float* __restrict__ proj,
                                                    float* __restrict__ partial,
                                                    float* __restrict__ ctx) {
    __shared__ unsigned short As[128][40];
    __shared__ unsigned short Pj[112][40];
    __shared__ float wmax[4][8];
    int tid = threadIdx.x;
    int r0 = blockIdx.x * 128;
    if (tid < 96) ctx[blockIdx.x * 96 + tid] = 0.0f;
    for (int idx = tid; idx < 112 * 8; idx += 256) {
        int m = idx >> 3, f4 = idx & 7;
        if (m < NB) {
            float4 va = *(const float4*)(proj + m * 32 + f4 * 4);
            bf16x4 pk = {(short)f2b(va.x), (short)f2b(va.y), (short)f2b(va.z), (short)f2b(va.w)};
            *(bf16x4*)&Pj[m][f4 * 4] = pk;
        } else {
            *(bf16x4*)&Pj[m][f4 * 4] = (bf16x4){0, 0, 0, 0};
        }
    }
    int arow = tid >> 1, ahalf = tid & 1;
    const unsigned short* ap = k + (size_t)(r0 + arow) * 32 + ahalf * 16;
    *(bf16x8*)&As[arow][ahalf * 16] = *(const bf16x8*)ap;
    *(bf16x8*)&As[arow][ahalf * 16 + 8] = *(const bf16x8*)(ap + 8);
    __syncthreads();
    int wave = tid >> 6, lane = tid & 63, lr = lane & 15, lg = lane >> 4;
    float mymax[4] = {-1e30f, -1e30f, -1e30f, -1e30f};
    #pragma unroll
    for (int mt = 0; mt < 2; ++mt) {
        bf16x8 af = *(bf16x8*)&As[(2 * wave + mt) * 16 + lr][lg * 8];
        #pragma unroll
        for (int nt = 0; nt < 7; ++nt) {
            bf16x8 bfp = *(bf16x8*)&Pj[nt * 16 + lr][lg * 8];
            f32x4 d = (f32x4){0.f, 0.f, 0.f, 0.f};
            d = __builtin_amdgcn_mfma_f32_16x16x32_bf16(af, bfp, d, 0, 0, 0);
            if (!(nt == 6 && lr >= 14)) {
                #pragma unroll
                for (int r = 0; r < 4; ++r) mymax[r] = fmaxf(mymax[r], d[r]);
            }
        }
    }
    #pragma unroll
    for (int r = 0; r < 4; ++r) {
        float v = mymax[r];
        v = fmaxf(v, __shfl_xor(v, 1));
        v = fmaxf(v, __shfl_xor(v, 2));
        v = fmaxf(v, __shfl_xor(v, 4));
        v = fmaxf(v, __shfl_xor(v, 8));
        v = fmaxf(v, __shfl_xor(v, 32));
        mymax[r] = v;
    }
    if (lane == 0 || lane == 16) {
        int hb = (lane >> 4) & 1;
        #pragma unroll
        for (int r = 0; r < 4; ++r) wmax[wave][4 * hb + r] = mymax[r];
    }
    __syncthreads();
    if (tid < 8) {
        float m = fmaxf(fmaxf(wmax[0][tid], wmax[1][tid]), fmaxf(wmax[2][tid], wmax[3][tid]));
        partial[blockIdx.x * 8 + tid] = m * c_dn;
    }
}

// ---------------- ctxg (16 n-chunks per bh; folded kmax reduction) ----------------
__global__ __launch_bounds__(256) void ctxg_kernel(const unsigned short* __restrict__ k,
                                                   const unsigned short* __restrict__ v,
                                                   const float* __restrict__ proj,
                                                   const float* __restrict__ partial,
                                                   float* __restrict__ ctx) {
    __shared__ __align__(16) char pool[34816];
    unsigned short (*As)[40] = (unsigned short(*)[40])pool;
    unsigned short (*KpT)[136] = (unsigned short(*)[136])pool;
    __shared__ unsigned short Pj[112][40];
    __shared__ unsigned short VsT[48][136];
    __shared__ float dg[128];
    __shared__ float redbuf[4];
    int tid = threadIdx.x;
    int bh = blockIdx.y, b = bh >> 3, h = bh & 7;
    int n_base = blockIdx.x * 512;
    {
        float m = fmaxf(partial[(size_t)(b * 512 + tid) * 8 + h],
                        partial[(size_t)(b * 512 + 256 + tid) * 8 + h]);
        #pragma unroll
        for (int off = 32; off; off >>= 1) m = fmaxf(m, __shfl_xor(m, off));
        if ((tid & 63) == 0) redbuf[tid >> 6] = m;
    }
    for (int idx = tid; idx < 112 * 8; idx += 256) {
        int m = idx >> 3, f4 = idx & 7;
        if (m < NB) {
            float4 va = *(const float4*)(proj + m * 32 + f4 * 4);
            bf16x4 pk = {(short)f2b(va.x), (short)f2b(va.y), (short)f2b(va.z), (short)f2b(va.w)};
            *(bf16x4*)&Pj[m][f4 * 4] = pk;
        } else {
            *(bf16x4*)&Pj[m][f4 * 4] = (bf16x4){0, 0, 0, 0};
        }
    }
    for (int idx = tid; idx < 16 * 136; idx += 256) KpT[112 + idx / 136][idx % 136] = 0;
    for (int idx = tid; idx < 16 * 128; idx += 256) {
        int rr = 32 + (idx >> 7), nn = idx & 127;
        VsT[rr][nn] = (rr == 32) ? (unsigned short)0x3F80 : (unsigned short)0;
    }
    __syncthreads();
    float mx = fmaxf(fmaxf(redbuf[0], redbuf[1]), fmaxf(redbuf[2], redbuf[3]));
    int wave = tid >> 6, lane = tid & 63, lr = lane & 15, lg = lane >> 4;
    int arow = tid >> 1, ahalf = tid & 1;
    f32x4 ctxacc[2][3];
    #pragma unroll
    for (int mt = 0; mt < 2; ++mt)
        #pragma unroll
        for (int nt = 0; nt < 3; ++nt) ctxacc[mt][nt] = (f32x4){0.f, 0.f, 0.f, 0.f};

    for (int ni = 0; ni < 4; ++ni) {
        int n0 = n_base + ni * 128;
        {
            const unsigned short* kp_ = k + ((size_t)(b * NSEQ + n0 + arow) * 256 + h * 32 + ahalf * 16);
            bf16x8 k0 = *(const bf16x8*)kp_;
            bf16x8 k1 = *(const bf16x8*)(kp_ + 8);
            *(bf16x8*)&As[arow][ahalf * 16] = k0;
            *(bf16x8*)&As[arow][ahalf * 16 + 8] = k1;
            float ssq = 0.f;
            #pragma unroll
            for (int e = 0; e < 8; ++e) {
                float a = b2f((unsigned short)k0[e]), bb = b2f((unsigned short)k1[e]);
                ssq += a * a + bb * bb;
            }
            ssq += __shfl_xor(ssq, 1);
            if (ahalf == 0) dg[arow] = ssq * c_diagf;
        }
        #pragma unroll
        for (int it = 0; it < 4; ++it) {
            int idx = it * 256 + tid;
            int nn = idx >> 3, f4 = idx & 7;
            bf16x4 vv = *(const bf16x4*)(v + ((size_t)(b * NSEQ + n0 + nn) * 256 + h * 32 + f4 * 4));
            VsT[f4 * 4 + 0][nn] = (unsigned short)vv[0];
            VsT[f4 * 4 + 1][nn] = (unsigned short)vv[1];
            VsT[f4 * 4 + 2][nn] = (unsigned short)vv[2];
            VsT[f4 * 4 + 3][nn] = (unsigned short)vv[3];
        }
        __syncthreads();
        f32x4 xds[2][7];
        #pragma unroll
        for (int mt = 0; mt < 2; ++mt) {
            bf16x8 af = *(bf16x8*)&As[(2 * wave + mt) * 16 + lr][lg * 8];
            #pragma unroll
            for (int nt = 0; nt < 7; ++nt) {
                bf16x8 bfp = *(bf16x8*)&Pj[nt * 16 + lr][lg * 8];
                f32x4 d = (f32x4){0.f, 0.f, 0.f, 0.f};
                xds[mt][nt] = __builtin_amdgcn_mfma_f32_16x16x32_bf16(af, bfp, d, 0, 0, 0);
            }
        }
        __syncthreads();
        #pragma unroll
        for (int mt = 0; mt < 2; ++mt)
            #pragma unroll
            for (int nt = 0; nt < 7; ++nt) {
                int m = nt * 16 + lr;
                #pragma unroll
                for (int r = 0; r < 4; ++r) {
                    int nn = (2 * wave + mt) * 16 + lg * 4 + r;
                    float kpv = (m < NB) ? c_ratio * (__expf(xds[mt][nt][r] * c_dn - dg[nn] - mx) + 1e-4f) : 0.f;
                    KpT[m][nn] = f2b(kpv);
                }
            }
        __syncthreads();
        #pragma unroll
        for (int ks = 0; ks < 4; ++ks)
            #pragma unroll
            for (int mt = 0; mt < 2; ++mt) {
                bf16x8 af2 = *(bf16x8*)&KpT[(2 * wave + mt) * 16 + lr][ks * 32 + lg * 8];
                #pragma unroll
                for (int nt = 0; nt < 3; ++nt) {
                    bf16x8 bf2v = *(bf16x8*)&VsT[nt * 16 + lr][ks * 32 + lg * 8];
                    ctxacc[mt][nt] = __builtin_amdgcn_mfma_f32_16x16x32_bf16(af2, bf2v, ctxacc[mt][nt], 0, 0, 0);
                }
            }
        __syncthreads();
    }
    #pragma unroll
    for (int mt = 0; mt < 2; ++mt)
        #pragma unroll
        for (int nt = 0; nt < 3; ++nt)
            #pragma unroll
            for (int r = 0; r < 4; ++r) {
                int m = (2 * wave + mt) * 16 + lg * 4 + r;
                atomicAdd(&ctx[((size_t)bh * 128 + m) * 48 + nt * 16 + lr], ctxacc[mt][nt][r]);
            }
}

// ---------------- og ----------------
__global__ __launch_bounds__(256) void og_kernel(const unsigned short* __restrict__ q,
                                                 const float* __restrict__ proj,
                                                 const float* __restrict__ ctx,
                                                 unsigned short* __restrict__ o) {
    __shared__ __align__(16) char pool[34816];
    unsigned short (*As)[40] = (unsigned short(*)[40])pool;
    unsigned short (*Qp)[136] = (unsigned short(*)[136])pool;
    __shared__ unsigned short Pj[112][40];
    __shared__ unsigned short CsT[48][136];
    __shared__ float dg[128];
    int tid = threadIdx.x;
    int bh = blockIdx.x >> 6, b = bh >> 3, h = bh & 7;
    int n0 = (blockIdx.x & 63) * 128;
    for (int idx = tid; idx < 112 * 8; idx += 256) {
        int m = idx >> 3, f4 = idx & 7;
        if (m < NB) {
            float4 va = *(const float4*)(proj + m * 32 + f4 * 4);
            bf16x4 pk = {(short)f2b(va.x), (short)f2b(va.y), (short)f2b(va.z), (short)f2b(va.w)};
            *(bf16x4*)&Pj[m][f4 * 4] = pk;
        } else {
            *(bf16x4*)&Pj[m][f4 * 4] = (bf16x4){0, 0, 0, 0};
        }
    }
    for (int idx = tid; idx < 128 * 12; idx += 256) {
        int m = idx / 12, c4 = idx - m * 12;
        float4 cv = *(const float4*)(ctx + ((size_t)bh * 128 + m) * 48 + c4 * 4);
        CsT[c4 * 4 + 0][m] = f2b(cv.x);
        CsT[c4 * 4 + 1][m] = f2b(cv.y);
        CsT[c4 * 4 + 2][m] = f2b(cv.z);
        CsT[c4 * 4 + 3][m] = f2b(cv.w);
    }
    int arow = tid >> 1, ahalf = tid & 1;
    {
        const unsigned short* qp_ = q + ((size_t)(b * NSEQ + n0 + arow) * 256 + h * 32 + ahalf * 16);
        bf16x8 q0 = *(const bf16x8*)qp_;
        bf16x8 q1 = *(const bf16x8*)(qp_ + 8);
        *(bf16x8*)&As[arow][ahalf * 16] = q0;
        *(bf16x8*)&As[arow][ahalf * 16 + 8] = q1;
        float ssq = 0.f;
        #pragma unroll
        for (int e = 0; e < 8; ++e) {
            float a = b2f((unsigned short)q0[e]), bb = b2f((unsigned short)q1[e]);
            ssq += a * a + bb * bb;
        }
        ssq += __shfl_xor(ssq, 1);
        if (ahalf == 0) dg[arow] = ssq * c_diagf;
    }
    __syncthreads();
    int wave = tid >> 6, lane = tid & 63, lr = lane & 15, lg = lane >> 4;
    f32x4 xds[2][7];
    #pragma unroll
    for (int mt = 0; mt < 2; ++mt) {
        bf16x8 af = *(bf16x8*)&As[(2 * wave + mt) * 16 + lr][lg * 8];
        #pragma unroll
        for (int nt = 0; nt < 7; ++nt) {
            bf16x8 bfp = *(bf16x8*)&Pj[nt * 16 + lr][lg * 8];
            f32x4 d = (f32x4){0.f, 0.f, 0.f, 0.f};
            xds[mt][nt] = __builtin_amdgcn_mfma_f32_16x16x32_bf16(af, bfp, d, 0, 0, 0);
        }
    }
    float rmax[2][4];
    #pragma unroll
    for (int mt = 0; mt < 2; ++mt)
        #pragma unroll
        for (int r = 0; r < 4; ++r) {
            float mv = -1e30f;
            #pragma unroll
            for (int nt = 0; nt < 7; ++nt)
                if (!(nt == 6 && lr >= 14)) mv = fmaxf(mv, xds[mt][nt][r]);
            mv = fmaxf(mv, __shfl_xor(mv, 1));
            mv = fmaxf(mv, __shfl_xor(mv, 2));
            mv = fmaxf(mv, __shfl_xor(mv, 4));
            mv = fmaxf(mv, __shfl_xor(mv, 8));
            rmax[mt][r] = mv;
        }
    __syncthreads();
    #pragma unroll
    for (int mt = 0; mt < 2; ++mt)
        #pragma unroll
        for (int r = 0; r < 4; ++r) {
            int row = (2 * wave + mt) * 16 + lg * 4 + r;
            #pragma unroll
            for (int nt = 0; nt < 7; ++nt) {
                int m = nt * 16 + lr;
                float qpv = (m < NB)
                    ? c_ratio * (__expf((xds[mt][nt][r] - rmax[mt][r]) * c_dn - dg[row]) + 1e-4f)
                    : 0.f;
                Qp[row][m] = f2b(qpv);
            }
            Qp[row][112 + lr] = 0;
        }
    __syncthreads();
    f32x4 oacc[2][3];
    #pragma unroll
    for (int mt = 0; mt < 2; ++mt)
        #pragma unroll
        for (int nt = 0; nt < 3; ++nt) oacc[mt][nt] = (f32x4){0.f, 0.f, 0.f, 0.f};
    #pragma unroll
    for (int ks = 0; ks < 4; ++ks)
        #pragma unroll
        for (int mt = 0; mt < 2; ++mt) {
            bf16x8 af2 = *(bf16x8*)&Qp[(2 * wave + mt) * 16 + lr][ks * 32 + lg * 8];
            #pragma unroll
            for (int nt = 0; nt < 3; ++nt) {
                bf16x8 bf2v = *(bf16x8*)&CsT[nt * 16 + lr][ks * 32 + lg * 8];
                oacc[mt][nt] = __builtin_amdgcn_mfma_f32_16x16x32_bf16(af2, bf2v, oacc[mt][nt], 0, 0, 0);
            }
        }
    #pragma unroll
    for (int mt = 0; mt < 2; ++mt)
        #pragma unroll
        for (int r = 0; r < 4; ++r) {
            int row = (2 * wave + mt) * 16 + lg * 4 + r;
            int n = n0 + row;
            float den = __shfl(oacc[mt][2][r], lane & 48);
            float inv = 1.0f / den;
            size_t base = (size_t)(b * NSEQ + n) * 256 + h * 32;
            o[base + lr] = f2b(oacc[mt][0][r] * inv);
            o[base + 16 + lr] = f2b(oacc[mt][1][r] * inv);
        }
}

extern "C" void kernel_launch(void* const* d_in, const int* in_sizes, int n_in,
                              void* d_out, int out_size, void* d_ws, size_t ws_size,
                              hipStream_t stream) {
    const float* x = (const float*)d_in[0];
    const float* proj = (const float*)d_in[1];
    const float* ln1_g = (const float*)d_in[2];
    const float* ln1_b = (const float*)d_in[3];
    const float* Wq = (const float*)d_in[4];
    const float* bq = (const float*)d_in[5];
    const float* Wk = (const float*)d_in[6];
    const float* bk = (const float*)d_in[7];
    const float* Wv = (const float*)d_in[8];
    const float* bv = (const float*)d_in[9];
    const float* Wo = (const float*)d_in[10];
    const float* bo = (const float*)d_in[11];
    const float* ln2_g = (const float*)d_in[12];
    const float* ln2_b = (const float*)d_in[13];
    const float* Wf1 = (const float*)d_in[14];
    const float* bf1 = (const float*)d_in[15];
    const float* Wf2 = (const float*)d_in[16];
    const float* bf2 = (const float*)d_in[17];

    float* hf = (float*)d_out;                       // final f32 output only
    const size_t ACT = (size_t)MROWS * DIM;
    unsigned short* y = (unsigned short*)d_ws;
    unsigned short* q = y + ACT;
    unsigned short* k = q + ACT;
    unsigned short* v = k + ACT;
    unsigned short* mid = v + ACT;                   // [32768][1024] bf16
    unsigned short* hb = mid + 4 * ACT;              // bf16 residual stream
    float* ctx = (float*)(hb + ACT);
    float* partial = ctx + (size_t)BH * 128 * 48;    // 2048*8 floats
    float* bqkv = partial + 2048 * 8;                // 4*768 floats
    unsigned short* wt = (unsigned short*)(bqkv + 4 * 768);
    unsigned short* o = y;                           // o aliases y

    const int WT_L = 786432;

    wt_kernel<<<dim3(8, 8, 4), 256, 0, stream>>>(Wq, wt + 0, 256, 256, WT_L);
    wt_kernel<<<dim3(8, 8, 4), 256, 0, stream>>>(Wk, wt + 65536, 256, 256, WT_L);
    wt_kernel<<<dim3(8, 8, 4), 256, 0, stream>>>(Wv, wt + 131072, 256, 256, WT_L);
    wt_kernel<<<dim3(8, 8, 4), 256, 0, stream>>>(Wo, wt + 196608, 256, 256, WT_L);
    wt_kernel<<<dim3(8, 32, 4), 256, 0, stream>>>(Wf1, wt + 262144, 256, 1024, WT_L);
    wt_kernel<<<dim3(32, 8, 4), 256, 0, stream>>>(Wf2, wt + 524288, 1024, 256, WT_L);
    bcat_kernel<<<4, 256, 0, stream>>>(bq, bk, bv, bqkv);

    // layer-0 entry: y = LN(x), hb = bf16(x) (cvt folded in; x read once)
    ln_kernel<<<MROWS / 4, 256, 0, stream>>>(x, ln1_g, ln1_b, y, hb);

    for (int i = 0; i < 4; ++i) {
        const float* proj_i = proj + (size_t)i * NB * DHEAD;
        const unsigned short* wl = wt + (size_t)i * WT_L;
        // --- attention (y holds ln1(h)) ---
        gemm_mfma<3><<<dim3(6, 256), 256, 0, stream>>>(y, wl + 0, bqkv + i * 768, q, 768, DIM);

        kmaxg_kernel<<<2048, 256, 0, stream>>>(k, proj_i, partial, ctx);   // also zeroes ctx
        ctxg_kernel<<<dim3(16, BH), 256, 0, stream>>>(k, v, proj_i, partial, ctx);  // folded kreduce
        og_kernel<<<BH * 64, 256, 0, stream>>>(q, proj_i, ctx, o);

        // Wo + residual(bf16) + fused ln2 -> hb(bf16), y
        gemm_ln<1, 0><<<dim3(1, MROWS / 64), 256, 0, stream>>>(o, wl + 196608, bo + i * DIM, hb, hb, y,
                                                               ln2_g + i * DIM, ln2_b + i * DIM, INNER);

        // --- FFN (FFN1 via 128x256 wide tile) ---
        gemm_wide<<<dim3(4, MROWS / 128), 256, 0, stream>>>(y, wl + 262144, bf1 + i * FFDIM, mid, FFDIM, DIM);
        if (i < 3) {
            gemm_ln<1, 0><<<dim3(1, MROWS / 64), 256, 0, stream>>>(mid, wl + 524288, bf2 + i * DIM, hb, hb, y,
                                                                   ln1_g + (i + 1) * DIM, ln1_b + (i + 1) * DIM, FFDIM);
        } else {
            gemm_ln<0, 1><<<dim3(1, MROWS / 64), 256, 0, stream>>>(mid, wl + 524288, bf2 + i * DIM, hb, hf, nullptr,
                                                                   nullptr, nullptr, FFDIM);
        }
    }
}

// Round 22
// 753.498 us; speedup vs baseline: 1.1246x; 1.1246x over previous
//
#include <hip/hip_runtime.h>
#include <math.h>

#define NSEQ 8192
#define BATCH 4
#define DIM 256
#define HEADS 8
#define DHEAD 32
#define NB 110
#define INNER 256
#define FFDIM 1024
#define MROWS (BATCH * NSEQ)   // 32768 rows
#define BH (BATCH * HEADS)     // 32

typedef __attribute__((ext_vector_type(8))) short bf16x8;
typedef __attribute__((ext_vector_type(4))) short bf16x4;
typedef __attribute__((ext_vector_type(4))) float f32x4;

typedef __attribute__((address_space(1))) const void* gas_cvp;
typedef __attribute__((address_space(3))) void* las_vp;

constexpr float c_dn = 0.42044820762685725f;     // 32^-0.25
constexpr float c_diagf = 0.08838834764831845f;  // 0.5*dn*dn
constexpr float c_ratio = 0.09534625892455922f;  // 110^-0.5

__device__ __forceinline__ unsigned short f2b(float f) {
    unsigned u = __float_as_uint(f);
    unsigned r = (u + 0x7FFFu + ((u >> 16) & 1u)) >> 16;
    return (unsigned short)r;
}
__device__ __forceinline__ float b2f(unsigned short u) {
    return __uint_as_float((unsigned)u << 16);
}

// ---------------- util ----------------
__global__ __launch_bounds__(256) void bcat_kernel(const float* __restrict__ bq,
                                                   const float* __restrict__ bk,
                                                   const float* __restrict__ bv,
                                                   float* __restrict__ out) {
    int l = blockIdx.x, t = threadIdx.x;
    out[l * 768 + t] = bq[l * 256 + t];
    out[l * 768 + 256 + t] = bk[l * 256 + t];
    out[l * 768 + 512 + t] = bv[l * 256 + t];
}

// ---------------- layer-0 entry: y = LN(x) AND hb = bf16(x) (folded cvt) ----------------
__global__ __launch_bounds__(256) void ln_kernel(const float* __restrict__ x,
                                                 const float* __restrict__ g,
                                                 const float* __restrict__ bta,
                                                 unsigned short* __restrict__ y,
                                                 unsigned short* __restrict__ hb) {
    int wave = threadIdx.x >> 6, lane = threadIdx.x & 63;
    int row = blockIdx.x * 4 + wave;
    const float* xr = x + (size_t)row * DIM;
    float4 v = *(const float4*)(xr + lane * 4);
    bf16x4 hcast;
    hcast[0] = (short)f2b(v.x);
    hcast[1] = (short)f2b(v.y);
    hcast[2] = (short)f2b(v.z);
    hcast[3] = (short)f2b(v.w);
    *(bf16x4*)(hb + (size_t)row * DIM + lane * 4) = hcast;
    float s = v.x + v.y + v.z + v.w;
    float sq = v.x * v.x + v.y * v.y + v.z * v.z + v.w * v.w;
    #pragma unroll
    for (int off = 32; off; off >>= 1) {
        s += __shfl_xor(s, off);
        sq += __shfl_xor(sq, off);
    }
    float mean = s * (1.0f / DIM);
    float var = sq * (1.0f / DIM) - mean * mean;
    float rstd = rsqrtf(var + 1e-5f);
    float4 gg = *(const float4*)(g + lane * 4);
    float4 bb = *(const float4*)(bta + lane * 4);
    bf16x4 o;
    o[0] = (short)f2b((v.x - mean) * rstd * gg.x + bb.x);
    o[1] = (short)f2b((v.y - mean) * rstd * gg.y + bb.y);
    o[2] = (short)f2b((v.z - mean) * rstd * gg.z + bb.z);
    o[3] = (short)f2b((v.w - mean) * rstd * gg.w + bb.w);
    *(bf16x4*)(y + (size_t)row * DIM + lane * 4) = o;
}

// ---------------- weight transpose+convert: out[l][n][k] = bf16(in[l][k][n]) ----------------
__global__ __launch_bounds__(256) void wt_kernel(const float* __restrict__ in,
                                                 unsigned short* __restrict__ out,
                                                 int K, int Nn, int lstride) {
    __shared__ float t32[32][33];
    int l = blockIdx.z;
    const float* inp = in + (size_t)l * K * Nn;
    unsigned short* outp = out + (size_t)l * lstride;
    int k0 = blockIdx.x * 32, n0 = blockIdx.y * 32;
    int tx = threadIdx.x & 31, ty = threadIdx.x >> 5;
    #pragma unroll
    for (int i = 0; i < 4; ++i)
        t32[ty + i * 8][tx] = inp[(size_t)(k0 + ty + i * 8) * Nn + n0 + tx];
    __syncthreads();
    #pragma unroll
    for (int i = 0; i < 4; ++i) {
        int r = ty + i * 8;  // n within tile
        outp[(size_t)(n0 + r) * K + k0 + tx] = f2b(t32[tx][r]);
    }
}

// ---------------- bf16 MFMA GEMM, 2-buffer pipeline + XCD swizzle (QKV / FFN1) ----------------
// EPI 0: +bias -> bf16 (LDS epilogue)   EPI 2: gelu(+bias) -> bf16 (scalar epilogue)
// EPI 3: +bias -> bf16 segmented (LDS epilogue)
template <int EPI>
__global__ __launch_bounds__(256) void gemm_mfma(const unsigned short* __restrict__ A,
                                                 const unsigned short* __restrict__ Wt,
                                                 const float* __restrict__ bias,
                                                 void* __restrict__ Cv,
                                                 int Nn, int K) {
    __shared__ __align__(16) unsigned short pool[16384];   // As[2][4096] | Bs[2][4096]; C-tile reuse
    unsigned short* AsP = pool;
    unsigned short* BsP = pool + 8192;
    int tid = threadIdx.x;
    int nwg = gridDim.x * gridDim.y;
    int orig = blockIdx.y * gridDim.x + blockIdx.x;
    int swz = (orig & 7) * (nwg >> 3) + (orig >> 3);
    int m0 = (swz / gridDim.x) * 128, n0 = (swz % gridDim.x) * 128;
    int wave = tid >> 6, lane = tid & 63;
    int wm = (wave >> 1) * 64, wn = (wave & 1) * 64;
    int lr = lane & 15, lg = lane >> 4;
    f32x4 acc[4][4];
    #pragma unroll
    for (int i = 0; i < 4; ++i)
        #pragma unroll
        for (int j = 0; j < 4; ++j) acc[i][j] = (f32x4){0.f, 0.f, 0.f, 0.f};

    int rowS[2], chS[2];
    #pragma unroll
    for (int j = 0; j < 2; ++j) {
        int f = wave * 128 + j * 64 + lane;
        rowS[j] = f >> 2;
        chS[j] = ((f & 3) ^ ((rowS[j] >> 1) & 3)) * 8;
    }
    int rdA[4], rdB[4];
    #pragma unroll
    for (int i = 0; i < 4; ++i) {
        int ra = wm + i * 16 + lr;
        rdA[i] = ra * 32 + (lg ^ ((ra >> 1) & 3)) * 8;
        int rb = wn + i * 16 + lr;
        rdB[i] = rb * 32 + (lg ^ ((rb >> 1) & 3)) * 8;
    }

    const int NT = K >> 5;
    #pragma unroll
    for (int j = 0; j < 2; ++j) {
        const unsigned short* srcA = A + (size_t)(m0 + rowS[j]) * K + chS[j];
        __builtin_amdgcn_global_load_lds((gas_cvp)srcA,
                                         (las_vp)(AsP + wave * 1024 + j * 512), 16, 0, 0);
        const unsigned short* srcB = Wt + (size_t)(n0 + rowS[j]) * K + chS[j];
        __builtin_amdgcn_global_load_lds((gas_cvp)srcB,
                                         (las_vp)(BsP + wave * 1024 + j * 512), 16, 0, 0);
    }
    for (int kt = 0; kt < NT; ++kt) {
        int cur = kt & 1;
        if (kt + 1 < NT) {
            int nxt = cur ^ 1;
            int koff = (kt + 1) * 32;
            #pragma unroll
            for (int j = 0; j < 2; ++j) {
                const unsigned short* srcA = A + (size_t)(m0 + rowS[j]) * K + koff + chS[j];
                __builtin_amdgcn_global_load_lds((gas_cvp)srcA,
                                                 (las_vp)(AsP + nxt * 4096 + wave * 1024 + j * 512), 16, 0, 0);
                const unsigned short* srcB = Wt + (size_t)(n0 + rowS[j]) * K + koff + chS[j];
                __builtin_amdgcn_global_load_lds((gas_cvp)srcB,
                                                 (las_vp)(BsP + nxt * 4096 + wave * 1024 + j * 512), 16, 0, 0);
            }
            asm volatile("s_waitcnt vmcnt(4)" ::: "memory");
        } else {
            asm volatile("s_waitcnt vmcnt(0)" ::: "memory");
        }
        __builtin_amdgcn_s_barrier();
        __builtin_amdgcn_sched_barrier(0);
        bf16x8 af[4], bfv[4];
        #pragma unroll
        for (int i = 0; i < 4; ++i) af[i] = *(bf16x8*)&AsP[cur * 4096 + rdA[i]];
        #pragma unroll
        for (int j = 0; j < 4; ++j) bfv[j] = *(bf16x8*)&BsP[cur * 4096 + rdB[j]];
        #pragma unroll
        for (int i = 0; i < 4; ++i)
            #pragma unroll
            for (int j = 0; j < 4; ++j)
                acc[i][j] = __builtin_amdgcn_mfma_f32_16x16x32_bf16(af[i], bfv[j], acc[i][j], 0, 0, 0);
        __builtin_amdgcn_sched_barrier(0);
        __builtin_amdgcn_s_barrier();
    }

    if (EPI == 2) {
        // scalar epilogue (measured better for FFN1's N=1024 row-major output)
        #pragma unroll
        for (int i = 0; i < 4; ++i) {
            #pragma unroll
            for (int j = 0; j < 4; ++j) {
                int col = n0 + wn + j * 16 + lr;
                float bv = bias[col];
                #pragma unroll
                for (int r = 0; r < 4; ++r) {
                    int row = m0 + wm + i * 16 + lg * 4 + r;
                    float u = acc[i][j][r] + bv;
                    float t = 1.5957691216057308f * (u + 0.044715f * u * u * u);
                    float gv = u / (1.0f + __expf(-t));
                    ((unsigned short*)Cv)[(size_t)row * Nn + col] = f2b(gv);
                }
            }
        }
    } else {
        // LDS-transposed bf16 epilogue
        #pragma unroll
        for (int i = 0; i < 4; ++i) {
            #pragma unroll
            for (int j = 0; j < 4; ++j) {
                int tcol = wn + j * 16 + lr;
                float bv = bias[n0 + tcol];
                #pragma unroll
                for (int r = 0; r < 4; ++r) {
                    int trow = wm + i * 16 + lg * 4 + r;
                    float c = acc[i][j][r] + bv;
                    pool[trow * 128 + (((tcol >> 3) ^ (trow & 7)) << 3) + (tcol & 7)] = f2b(c);
                }
            }
        }
        __syncthreads();
        #pragma unroll
        for (int cch = 0; cch < 8; ++cch) {
            int g = cch * 256 + tid;
            int row = g >> 4, cc = g & 15;
            bf16x8 val = *(bf16x8*)&pool[row * 128 + ((cc ^ (row & 7)) << 3)];
            int grow = m0 + row;
            int gcol = n0 + cc * 8;
            if (EPI == 3) {
                size_t idx = (size_t)(gcol >> 8) * ((size_t)MROWS * DIM) + (size_t)grow * 256 + (gcol & 255);
                *(bf16x8*)((unsigned short*)Cv + idx) = val;
            } else {
                *(bf16x8*)((unsigned short*)Cv + (size_t)grow * Nn + gcol) = val;
            }
        }
    }
}

// ---------------- gemm_ln: C=A@Wt^T+bias+res(bf16) -> h(bf16 or f32); optional fused LN -> y ----------------
template <int DO_LN, int F32OUT>
__global__ __launch_bounds__(256) void gemm_ln(const unsigned short* __restrict__ A,
                                               const unsigned short* __restrict__ Wt,
                                               const float* __restrict__ bias,
                                               const unsigned short* __restrict__ res,
                                               void* __restrict__ hout,
                                               unsigned short* __restrict__ yout,
                                               const float* __restrict__ gam,
                                               const float* __restrict__ bet,
                                               int K) {
    __shared__ __align__(16) unsigned short As[2][64 * 32];
    __shared__ __align__(16) unsigned short Bs[2][256 * 32];
    int tid = threadIdx.x;
    int nwg = gridDim.y;
    int orig = blockIdx.y;
    int swz = (orig & 7) * (nwg >> 3) + (orig >> 3);
    int m0 = swz * 64;
    int wave = tid >> 6, lane = tid & 63;
    int lr = lane & 15, lg = lane >> 4;

    f32x4 acc[16];
    #pragma unroll
    for (int j = 0; j < 16; ++j) acc[j] = (f32x4){0.f, 0.f, 0.f, 0.f};

    int fA = wave * 64 + lane;
    int rowA = fA >> 2, chA = ((fA & 3) ^ ((rowA >> 1) & 3)) * 8;
    int rowB[4], chB[4];
    #pragma unroll
    for (int j = 0; j < 4; ++j) {
        int f = wave * 256 + j * 64 + lane;
        rowB[j] = f >> 2;
        chB[j] = ((f & 3) ^ ((rowB[j] >> 1) & 3)) * 8;
    }
    int raA = wave * 16 + lr;
    int rdAo = raA * 32 + (lg ^ ((raA >> 1) & 3)) * 8;
    int rdBo[16];
    #pragma unroll
    for (int j = 0; j < 16; ++j) {
        int rb = j * 16 + lr;
        rdBo[j] = rb * 32 + (lg ^ ((rb >> 1) & 3)) * 8;
    }

    const int NT = K >> 5;
    {
        const unsigned short* srcA = A + (size_t)(m0 + rowA) * K + chA;
        __builtin_amdgcn_global_load_lds((gas_cvp)srcA, (las_vp)(&As[0][wave * 512]), 16, 0, 0);
        #pragma unroll
        for (int j = 0; j < 4; ++j) {
            const unsigned short* srcB = Wt + (size_t)rowB[j] * K + chB[j];
            __builtin_amdgcn_global_load_lds((gas_cvp)srcB, (las_vp)(&Bs[0][wave * 2048 + j * 512]), 16, 0, 0);
        }
    }
    for (int kt = 0; kt < NT; ++kt) {
        int cur = kt & 1;
        if (kt + 1 < NT) {
            int nxt = cur ^ 1;
            int koff = (kt + 1) * 32;
            const unsigned short* srcA = A + (size_t)(m0 + rowA) * K + koff + chA;
            __builtin_amdgcn_global_load_lds((gas_cvp)srcA, (las_vp)(&As[nxt][wave * 512]), 16, 0, 0);
            #pragma unroll
            for (int j = 0; j < 4; ++j) {
                const unsigned short* srcB = Wt + (size_t)rowB[j] * K + koff + chB[j];
                __builtin_amdgcn_global_load_lds((gas_cvp)srcB, (las_vp)(&Bs[nxt][wave * 2048 + j * 512]), 16, 0, 0);
            }
            asm volatile("s_waitcnt vmcnt(5)" ::: "memory");
        } else {
            asm volatile("s_waitcnt vmcnt(0)" ::: "memory");
        }
        __builtin_amdgcn_s_barrier();
        __builtin_amdgcn_sched_barrier(0);
        bf16x8 af = *(bf16x8*)&As[cur][rdAo];
        #pragma unroll
        for (int j = 0; j < 16; ++j) {
            bf16x8 bv = *(bf16x8*)&Bs[cur][rdBo[j]];
            acc[j] = __builtin_amdgcn_mfma_f32_16x16x32_bf16(af, bv, acc[j], 0, 0, 0);
        }
        __builtin_amdgcn_sched_barrier(0);
        __builtin_amdgcn_s_barrier();
    }

    float rs[4] = {0.f, 0.f, 0.f, 0.f};
    float rq[4] = {0.f, 0.f, 0.f, 0.f};
    #pragma unroll
    for (int j = 0; j < 16; ++j) {
        int col = j * 16 + lr;
        float bv = bias[col];
        #pragma unroll
        for (int r = 0; r < 4; ++r) {
            int row = m0 + wave * 16 + lg * 4 + r;
            float c = acc[j][r] + bv + b2f(res[(size_t)row * 256 + col]);
            if (F32OUT) ((float*)hout)[(size_t)row * 256 + col] = c;
            else ((unsigned short*)hout)[(size_t)row * 256 + col] = f2b(c);
            acc[j][r] = c;
            if (DO_LN) { rs[r] += c; rq[r] += c * c; }
        }
    }
    if (DO_LN) {
        #pragma unroll
        for (int r = 0; r < 4; ++r) {
            float s = rs[r], sq = rq[r];
            s += __shfl_xor(s, 1);  sq += __shfl_xor(sq, 1);
            s += __shfl_xor(s, 2);  sq += __shfl_xor(sq, 2);
            s += __shfl_xor(s, 4);  sq += __shfl_xor(sq, 4);
            s += __shfl_xor(s, 8);  sq += __shfl_xor(sq, 8);
            rs[r] = s; rq[r] = sq;
        }
        #pragma unroll
        for (int r = 0; r < 4; ++r) {
            float mean = rs[r] * (1.0f / 256.0f);
            float var = rq[r] * (1.0f / 256.0f) - mean * mean;
            rs[r] = mean;
            rq[r] = rsqrtf(var + 1e-5f);
        }
        #pragma unroll
        for (int j = 0; j < 16; ++j) {
            int col = j * 16 + lr;
            float gv = gam[col], bb = bet[col];
            #pragma unroll
            for (int r = 0; r < 4; ++r) {
                int row = m0 + wave * 16 + lg * 4 + r;
                float yv = (acc[j][r] - rs[r]) * rq[r] * gv + bb;
                yout[(size_t)row * 256 + col] = f2b(yv);
            }
        }
    }
}

// ---------------- kmaxg (+ folded ctx zeroing) ----------------
__global__ __launch_bounds__(256) void kmaxg_kernel(const unsigned short* __restrict__ k,
                                                    const float* __restrict__ proj,
                                                    float* __restrict__ partial,
                                                    float* __restrict__ ctx) {
    __shared__ unsigned short As[128][40];
    __shared__ unsigned short Pj[112][40];
    __shared__ float wmax[4][8];
    int tid = threadIdx.x;
    int r0 = blockIdx.x * 128;
    if (tid < 96) ctx[blockIdx.x * 96 + tid] = 0.0f;
    for (int idx = tid; idx < 112 * 8; idx += 256) {
        int m = idx >> 3, f4 = idx & 7;
        if (m < NB) {
            float4 va = *(const float4*)(proj + m * 32 + f4 * 4);
            bf16x4 pk = {(short)f2b(va.x), (short)f2b(va.y), (short)f2b(va.z), (short)f2b(va.w)};
            *(bf16x4*)&Pj[m][f4 * 4] = pk;
        } else {
            *(bf16x4*)&Pj[m][f4 * 4] = (bf16x4){0, 0, 0, 0};
        }
    }
    int arow = tid >> 1, ahalf = tid & 1;
    const unsigned short* ap = k + (size_t)(r0 + arow) * 32 + ahalf * 16;
    *(bf16x8*)&As[arow][ahalf * 16] = *(const bf16x8*)ap;
    *(bf16x8*)&As[arow][ahalf * 16 + 8] = *(const bf16x8*)(ap + 8);
    __syncthreads();
    int wave = tid >> 6, lane = tid & 63, lr = lane & 15, lg = lane >> 4;
    float mymax[4] = {-1e30f, -1e30f, -1e30f, -1e30f};
    #pragma unroll
    for (int mt = 0; mt < 2; ++mt) {
        bf16x8 af = *(bf16x8*)&As[(2 * wave + mt) * 16 + lr][lg * 8];
        #pragma unroll
        for (int nt = 0; nt < 7; ++nt) {
            bf16x8 bfp = *(bf16x8*)&Pj[nt * 16 + lr][lg * 8];
            f32x4 d = (f32x4){0.f, 0.f, 0.f, 0.f};
            d = __builtin_amdgcn_mfma_f32_16x16x32_bf16(af, bfp, d, 0, 0, 0);
            if (!(nt == 6 && lr >= 14)) {
                #pragma unroll
                for (int r = 0; r < 4; ++r) mymax[r] = fmaxf(mymax[r], d[r]);
            }
        }
    }
    #pragma unroll
    for (int r = 0; r < 4; ++r) {
        float v = mymax[r];
        v = fmaxf(v, __shfl_xor(v, 1));
        v = fmaxf(v, __shfl_xor(v, 2));
        v = fmaxf(v, __shfl_xor(v, 4));
        v = fmaxf(v, __shfl_xor(v, 8));
        v = fmaxf(v, __shfl_xor(v, 32));
        mymax[r] = v;
    }
    if (lane == 0 || lane == 16) {
        int hb = (lane >> 4) & 1;
        #pragma unroll
        for (int r = 0; r < 4; ++r) wmax[wave][4 * hb + r] = mymax[r];
    }
    __syncthreads();
    if (tid < 8) {
        float m = fmaxf(fmaxf(wmax[0][tid], wmax[1][tid]), fmaxf(wmax[2][tid], wmax[3][tid]));
        partial[blockIdx.x * 8 + tid] = m * c_dn;
    }
}

// ---------------- ctxg (16 n-chunks per bh; folded kmax reduction) ----------------
__global__ __launch_bounds__(256) void ctxg_kernel(const unsigned short* __restrict__ k,
                                                   const unsigned short* __restrict__ v,
                                                   const float* __restrict__ proj,
                                                   const float* __restrict__ partial,
                                                   float* __restrict__ ctx) {
    __shared__ __align__(16) char pool[34816];
    unsigned short (*As)[40] = (unsigned short(*)[40])pool;
    unsigned short (*KpT)[136] = (unsigned short(*)[136])pool;
    __shared__ unsigned short Pj[112][40];
    __shared__ unsigned short VsT[48][136];
    __shared__ float dg[128];
    __shared__ float redbuf[4];
    int tid = threadIdx.x;
    int bh = blockIdx.y, b = bh >> 3, h = bh & 7;
    int n_base = blockIdx.x * 512;
    {
        float m = fmaxf(partial[(size_t)(b * 512 + tid) * 8 + h],
                        partial[(size_t)(b * 512 + 256 + tid) * 8 + h]);
        #pragma unroll
        for (int off = 32; off; off >>= 1) m = fmaxf(m, __shfl_xor(m, off));
        if ((tid & 63) == 0) redbuf[tid >> 6] = m;
    }
    for (int idx = tid; idx < 112 * 8; idx += 256) {
        int m = idx >> 3, f4 = idx & 7;
        if (m < NB) {
            float4 va = *(const float4*)(proj + m * 32 + f4 * 4);
            bf16x4 pk = {(short)f2b(va.x), (short)f2b(va.y), (short)f2b(va.z), (short)f2b(va.w)};
            *(bf16x4*)&Pj[m][f4 * 4] = pk;
        } else {
            *(bf16x4*)&Pj[m][f4 * 4] = (bf16x4){0, 0, 0, 0};
        }
    }
    for (int idx = tid; idx < 16 * 136; idx += 256) KpT[112 + idx / 136][idx % 136] = 0;
    for (int idx = tid; idx < 16 * 128; idx += 256) {
        int rr = 32 + (idx >> 7), nn = idx & 127;
        VsT[rr][nn] = (rr == 32) ? (unsigned short)0x3F80 : (unsigned short)0;
    }
    __syncthreads();
    float mx = fmaxf(fmaxf(redbuf[0], redbuf[1]), fmaxf(redbuf[2], redbuf[3]));
    int wave = tid >> 6, lane = tid & 63, lr = lane & 15, lg = lane >> 4;
    int arow = tid >> 1, ahalf = tid & 1;
    f32x4 ctxacc[2][3];
    #pragma unroll
    for (int mt = 0; mt < 2; ++mt)
        #pragma unroll
        for (int nt = 0; nt < 3; ++nt) ctxacc[mt][nt] = (f32x4){0.f, 0.f, 0.f, 0.f};

    for (int ni = 0; ni < 4; ++ni) {
        int n0 = n_base + ni * 128;
        {
            const unsigned short* kp_ = k + ((size_t)(b * NSEQ + n0 + arow) * 256 + h * 32 + ahalf * 16);
            bf16x8 k0 = *(const bf16x8*)kp_;
            bf16x8 k1 = *(const bf16x8*)(kp_ + 8);
            *(bf16x8*)&As[arow][ahalf * 16] = k0;
            *(bf16x8*)&As[arow][ahalf * 16 + 8] = k1;
            float ssq = 0.f;
            #pragma unroll
            for (int e = 0; e < 8; ++e) {
                float a = b2f((unsigned short)k0[e]), bb = b2f((unsigned short)k1[e]);
                ssq += a * a + bb * bb;
            }
            ssq += __shfl_xor(ssq, 1);
            if (ahalf == 0) dg[arow] = ssq * c_diagf;
        }
        #pragma unroll
        for (int it = 0; it < 4; ++it) {
            int idx = it * 256 + tid;
            int nn = idx >> 3, f4 = idx & 7;
            bf16x4 vv = *(const bf16x4*)(v + ((size_t)(b * NSEQ + n0 + nn) * 256 + h * 32 + f4 * 4));
            VsT[f4 * 4 + 0][nn] = (unsigned short)vv[0];
            VsT[f4 * 4 + 1][nn] = (unsigned short)vv[1];
            VsT[f4 * 4 + 2][nn] = (unsigned short)vv[2];
            VsT[f4 * 4 + 3][nn] = (unsigned short)vv[3];
        }
        __syncthreads();
        f32x4 xds[2][7];
        #pragma unroll
        for (int mt = 0; mt < 2; ++mt) {
            bf16x8 af = *(bf16x8*)&As[(2 * wave + mt) * 16 + lr][lg * 8];
            #pragma unroll
            for (int nt = 0; nt < 7; ++nt) {
                bf16x8 bfp = *(bf16x8*)&Pj[nt * 16 + lr][lg * 8];
                f32x4 d = (f32x4){0.f, 0.f, 0.f, 0.f};
                xds[mt][nt] = __builtin_amdgcn_mfma_f32_16x16x32_bf16(af, bfp, d, 0, 0, 0);
            }
        }
        __syncthreads();
        #pragma unroll
        for (int mt = 0; mt < 2; ++mt)
            #pragma unroll
            for (int nt = 0; nt < 7; ++nt) {
                int m = nt * 16 + lr;
                #pragma unroll
                for (int r = 0; r < 4; ++r) {
                    int nn = (2 * wave + mt) * 16 + lg * 4 + r;
                    float kpv = (m < NB) ? c_ratio * (__expf(xds[mt][nt][r] * c_dn - dg[nn] - mx) + 1e-4f) : 0.f;
                    KpT[m][nn] = f2b(kpv);
                }
            }
        __syncthreads();
        #pragma unroll
        for (int ks = 0; ks < 4; ++ks)
            #pragma unroll
            for (int mt = 0; mt < 2; ++mt) {
                bf16x8 af2 = *(bf16x8*)&KpT[(2 * wave + mt) * 16 + lr][ks * 32 + lg * 8];
                #pragma unroll
                for (int nt = 0; nt < 3; ++nt) {
                    bf16x8 bf2v = *(bf16x8*)&VsT[nt * 16 + lr][ks * 32 + lg * 8];
                    ctxacc[mt][nt] = __builtin_amdgcn_mfma_f32_16x16x32_bf16(af2, bf2v, ctxacc[mt][nt], 0, 0, 0);
                }
            }
        __syncthreads();
    }
    #pragma unroll
    for (int mt = 0; mt < 2; ++mt)
        #pragma unroll
        for (int nt = 0; nt < 3; ++nt)
            #pragma unroll
            for (int r = 0; r < 4; ++r) {
                int m = (2 * wave + mt) * 16 + lg * 4 + r;
                atomicAdd(&ctx[((size_t)bh * 128 + m) * 48 + nt * 16 + lr], ctxacc[mt][nt][r]);
            }
}

// ---------------- og ----------------
__global__ __launch_bounds__(256) void og_kernel(const unsigned short* __restrict__ q,
                                                 const float* __restrict__ proj,
                                                 const float* __restrict__ ctx,
                                                 unsigned short* __restrict__ o) {
    __shared__ __align__(16) char pool[34816];
    unsigned short (*As)[40] = (unsigned short(*)[40])pool;
    unsigned short (*Qp)[136] = (unsigned short(*)[136])pool;
    __shared__ unsigned short Pj[112][40];
    __shared__ unsigned short CsT[48][136];
    __shared__ float dg[128];
    int tid = threadIdx.x;
    int bh = blockIdx.x >> 6, b = bh >> 3, h = bh & 7;
    int n0 = (blockIdx.x & 63) * 128;
    for (int idx = tid; idx < 112 * 8; idx += 256) {
        int m = idx >> 3, f4 = idx & 7;
        if (m < NB) {
            float4 va = *(const float4*)(proj + m * 32 + f4 * 4);
            bf16x4 pk = {(short)f2b(va.x), (short)f2b(va.y), (short)f2b(va.z), (short)f2b(va.w)};
            *(bf16x4*)&Pj[m][f4 * 4] = pk;
        } else {
            *(bf16x4*)&Pj[m][f4 * 4] = (bf16x4){0, 0, 0, 0};
        }
    }
    for (int idx = tid; idx < 128 * 12; idx += 256) {
        int m = idx / 12, c4 = idx - m * 12;
        float4 cv = *(const float4*)(ctx + ((size_t)bh * 128 + m) * 48 + c4 * 4);
        CsT[c4 * 4 + 0][m] = f2b(cv.x);
        CsT[c4 * 4 + 1][m] = f2b(cv.y);
        CsT[c4 * 4 + 2][m] = f2b(cv.z);
        CsT[c4 * 4 + 3][m] = f2b(cv.w);
    }
    int arow = tid >> 1, ahalf = tid & 1;
    {
        const unsigned short* qp_ = q + ((size_t)(b * NSEQ + n0 + arow) * 256 + h * 32 + ahalf * 16);
        bf16x8 q0 = *(const bf16x8*)qp_;
        bf16x8 q1 = *(const bf16x8*)(qp_ + 8);
        *(bf16x8*)&As[arow][ahalf * 16] = q0;
        *(bf16x8*)&As[arow][ahalf * 16 + 8] = q1;
        float ssq = 0.f;
        #pragma unroll
        for (int e = 0; e < 8; ++e) {
            float a = b2f((unsigned short)q0[e]), bb = b2f((unsigned short)q1[e]);
            ssq += a * a + bb * bb;
        }
        ssq += __shfl_xor(ssq, 1);
        if (ahalf == 0) dg[arow] = ssq * c_diagf;
    }
    __syncthreads();
    int wave = tid >> 6, lane = tid & 63, lr = lane & 15, lg = lane >> 4;
    f32x4 xds[2][7];
    #pragma unroll
    for (int mt = 0; mt < 2; ++mt) {
        bf16x8 af = *(bf16x8*)&As[(2 * wave + mt) * 16 + lr][lg * 8];
        #pragma unroll
        for (int nt = 0; nt < 7; ++nt) {
            bf16x8 bfp = *(bf16x8*)&Pj[nt * 16 + lr][lg * 8];
            f32x4 d = (f32x4){0.f, 0.f, 0.f, 0.f};
            xds[mt][nt] = __builtin_amdgcn_mfma_f32_16x16x32_bf16(af, bfp, d, 0, 0, 0);
        }
    }
    float rmax[2][4];
    #pragma unroll
    for (int mt = 0; mt < 2; ++mt)
        #pragma unroll
        for (int r = 0; r < 4; ++r) {
            float mv = -1e30f;
            #pragma unroll
            for (int nt = 0; nt < 7; ++nt)
                if (!(nt == 6 && lr >= 14)) mv = fmaxf(mv, xds[mt][nt][r]);
            mv = fmaxf(mv, __shfl_xor(mv, 1));
            mv = fmaxf(mv, __shfl_xor(mv, 2));
            mv = fmaxf(mv, __shfl_xor(mv, 4));
            mv = fmaxf(mv, __shfl_xor(mv, 8));
            rmax[mt][r] = mv;
        }
    __syncthreads();
    #pragma unroll
    for (int mt = 0; mt < 2; ++mt)
        #pragma unroll
        for (int r = 0; r < 4; ++r) {
            int row = (2 * wave + mt) * 16 + lg * 4 + r;
            #pragma unroll
            for (int nt = 0; nt < 7; ++nt) {
                int m = nt * 16 + lr;
                float qpv = (m < NB)
                    ? c_ratio * (__expf((xds[mt][nt][r] - rmax[mt][r]) * c_dn - dg[row]) + 1e-4f)
                    : 0.f;
                Qp[row][m] = f2b(qpv);
            }
            Qp[row][112 + lr] = 0;
        }
    __syncthreads();
    f32x4 oacc[2][3];
    #pragma unroll
    for (int mt = 0; mt < 2; ++mt)
        #pragma unroll
        for (int nt = 0; nt < 3; ++nt) oacc[mt][nt] = (f32x4){0.f, 0.f, 0.f, 0.f};
    #pragma unroll
    for (int ks = 0; ks < 4; ++ks)
        #pragma unroll
        for (int mt = 0; mt < 2; ++mt) {
            bf16x8 af2 = *(bf16x8*)&Qp[(2 * wave + mt) * 16 + lr][ks * 32 + lg * 8];
            #pragma unroll
            for (int nt = 0; nt < 3; ++nt) {
                bf16x8 bf2v = *(bf16x8*)&CsT[nt * 16 + lr][ks * 32 + lg * 8];
                oacc[mt][nt] = __builtin_amdgcn_mfma_f32_16x16x32_bf16(af2, bf2v, oacc[mt][nt], 0, 0, 0);
            }
        }
    #pragma unroll
    for (int mt = 0; mt < 2; ++mt)
        #pragma unroll
        for (int r = 0; r < 4; ++r) {
            int row = (2 * wave + mt) * 16 + lg * 4 + r;
            int n = n0 + row;
            float den = __shfl(oacc[mt][2][r], lane & 48);
            float inv = 1.0f / den;
            size_t base = (size_t)(b * NSEQ + n) * 256 + h * 32;
            o[base + lr] = f2b(oacc[mt][0][r] * inv);
            o[base + 16 + lr] = f2b(oacc[mt][1][r] * inv);
        }
}

extern "C" void kernel_launch(void* const* d_in, const int* in_sizes, int n_in,
                              void* d_out, int out_size, void* d_ws, size_t ws_size,
                              hipStream_t stream) {
    const float* x = (const float*)d_in[0];
    const float* proj = (const float*)d_in[1];
    const float* ln1_g = (const float*)d_in[2];
    const float* ln1_b = (const float*)d_in[3];
    const float* Wq = (const float*)d_in[4];
    const float* bq = (const float*)d_in[5];
    const float* Wk = (const float*)d_in[6];
    const float* bk = (const float*)d_in[7];
    const float* Wv = (const float*)d_in[8];
    const float* bv = (const float*)d_in[9];
    const float* Wo = (const float*)d_in[10];
    const float* bo = (const float*)d_in[11];
    const float* ln2_g = (const float*)d_in[12];
    const float* ln2_b = (const float*)d_in[13];
    const float* Wf1 = (const float*)d_in[14];
    const float* bf1 = (const float*)d_in[15];
    const float* Wf2 = (const float*)d_in[16];
    const float* bf2 = (const float*)d_in[17];

    float* hf = (float*)d_out;                       // final f32 output only
    const size_t ACT = (size_t)MROWS * DIM;
    unsigned short* y = (unsigned short*)d_ws;
    unsigned short* q = y + ACT;
    unsigned short* k = q + ACT;
    unsigned short* v = k + ACT;
    unsigned short* mid = v + ACT;                   // [32768][1024] bf16
    unsigned short* hb = mid + 4 * ACT;              // bf16 residual stream
    float* ctx = (float*)(hb + ACT);
    float* partial = ctx + (size_t)BH * 128 * 48;    // 2048*8 floats
    float* bqkv = partial + 2048 * 8;                // 4*768 floats
    unsigned short* wt = (unsigned short*)(bqkv + 4 * 768);
    unsigned short* o = y;                           // o aliases y

    const int WT_L = 786432;

    wt_kernel<<<dim3(8, 8, 4), 256, 0, stream>>>(Wq, wt + 0, 256, 256, WT_L);
    wt_kernel<<<dim3(8, 8, 4), 256, 0, stream>>>(Wk, wt + 65536, 256, 256, WT_L);
    wt_kernel<<<dim3(8, 8, 4), 256, 0, stream>>>(Wv, wt + 131072, 256, 256, WT_L);
    wt_kernel<<<dim3(8, 8, 4), 256, 0, stream>>>(Wo, wt + 196608, 256, 256, WT_L);
    wt_kernel<<<dim3(8, 32, 4), 256, 0, stream>>>(Wf1, wt + 262144, 256, 1024, WT_L);
    wt_kernel<<<dim3(32, 8, 4), 256, 0, stream>>>(Wf2, wt + 524288, 1024, 256, WT_L);
    bcat_kernel<<<4, 256, 0, stream>>>(bq, bk, bv, bqkv);

    // layer-0 entry: y = LN(x), hb = bf16(x) (cvt folded in; x read once)
    ln_kernel<<<MROWS / 4, 256, 0, stream>>>(x, ln1_g, ln1_b, y, hb);

    for (int i = 0; i < 4; ++i) {
        const float* proj_i = proj + (size_t)i * NB * DHEAD;
        const unsigned short* wl = wt + (size_t)i * WT_L;
        // --- attention (y holds ln1(h)) ---
        gemm_mfma<3><<<dim3(6, 256), 256, 0, stream>>>(y, wl + 0, bqkv + i * 768, q, 768, DIM);

        kmaxg_kernel<<<2048, 256, 0, stream>>>(k, proj_i, partial, ctx);   // also zeroes ctx
        ctxg_kernel<<<dim3(16, BH), 256, 0, stream>>>(k, v, proj_i, partial, ctx);  // folded kreduce
        og_kernel<<<BH * 64, 256, 0, stream>>>(q, proj_i, ctx, o);

        // Wo + residual(bf16) + fused ln2 -> hb(bf16), y
        gemm_ln<1, 0><<<dim3(1, MROWS / 64), 256, 0, stream>>>(o, wl + 196608, bo + i * DIM, hb, hb, y,
                                                               ln2_g + i * DIM, ln2_b + i * DIM, INNER);

        // --- FFN ---
        gemm_mfma<2><<<dim3(8, 256), 256, 0, stream>>>(y, wl + 262144, bf1 + i * FFDIM, mid, FFDIM, DIM);
        if (i < 3) {
            gemm_ln<1, 0><<<dim3(1, MROWS / 64), 256, 0, stream>>>(mid, wl + 524288, bf2 + i * DIM, hb, hb, y,
                                                                   ln1_g + (i + 1) * DIM, ln1_b + (i + 1) * DIM, FFDIM);
        } else {
            gemm_ln<0, 1><<<dim3(1, MROWS / 64), 256, 0, stream>>>(mid, wl + 524288, bf2 + i * DIM, hb, hf, nullptr,
                                                                   nullptr, nullptr, FFDIM);
        }
    }
}